// Round 1
// baseline (299.268 us; speedup 1.0000x reference)
//
#include <hip/hip_runtime.h>

#define B_ 4
#define C_ 256
#define CI_ 128
#define HW_ 4096

typedef _Float16 f16x8 __attribute__((ext_vector_type(8)));
typedef _Float16 f16x4 __attribute__((ext_vector_type(4)));
typedef _Float16 f16x2 __attribute__((ext_vector_type(2)));
typedef float f32x16 __attribute__((ext_vector_type(16)));
typedef float f32x4 __attribute__((ext_vector_type(4)));

__device__ __forceinline__ f32x16 mfma16(f16x8 a, f16x8 b, f32x16 c) {
  return __builtin_amdgcn_mfma_f32_32x32x16_f16(a, b, c, 0, 0, 0);
}

// ---------------- K0a: x (b, ch, sp) fp32 -> xT (b, sp, ch) fp16 ----------------
__global__ __launch_bounds__(256) void k0_transpose(const float* __restrict__ x,
                                                    _Float16* __restrict__ xT) {
  __shared__ _Float16 Lt[64 * 66];  // stride 66 to dodge bank conflicts
  int t = threadIdx.x;
  int sp0 = blockIdx.x * 64;
  int ch0 = blockIdx.y * 64;
  int b = blockIdx.z;
  const float* xb = x + (size_t)b * C_ * HW_;
#pragma unroll
  for (int i = 0; i < 16; ++i) {
    int ch = i * 4 + (t >> 6);
    int sp = t & 63;
    float v = xb[(size_t)(ch0 + ch) * HW_ + sp0 + sp];
    Lt[ch * 66 + sp] = (_Float16)v;
  }
  __syncthreads();
  _Float16* xTb = xT + ((size_t)b * HW_ + sp0) * C_ + ch0;
  int c2 = t & 31;
  int spb = t >> 5;
#pragma unroll
  for (int j = 0; j < 8; ++j) {
    int sp = spb + j * 8;
    f16x2 pr;
    pr.x = Lt[(2 * c2) * 66 + sp];
    pr.y = Lt[(2 * c2 + 1) * 66 + sp];
    *(f16x2*)&xTb[(size_t)sp * C_ + 2 * c2] = pr;
  }
}

// ---------------- K0b: weights fp32 -> fp16 [theta|phi|g|out] ----------------
__global__ __launch_bounds__(256) void k0_wconv(const float* __restrict__ tw,
                                                const float* __restrict__ pw,
                                                const float* __restrict__ gw,
                                                const float* __restrict__ ow,
                                                _Float16* __restrict__ w16) {
  int gid = blockIdx.x * 256 + threadIdx.x;  // 0..32767 float4s
  int ti = gid >> 13;
  int off = (gid & 8191) * 4;
  const float* src = (ti == 0) ? tw : (ti == 1) ? pw : (ti == 2) ? gw : ow;
  f32x4 v = *(const f32x4*)&src[off];
  f16x4 hv;
  hv[0] = (_Float16)v[0]; hv[1] = (_Float16)v[1];
  hv[2] = (_Float16)v[2]; hv[3] = (_Float16)v[3];
  *(f16x4*)&w16[(size_t)ti * 32768 + off] = hv;
}

// ---------------- K1: projections theta/phi -> (hw,ci), g -> (ci,hw) ----------------
__global__ __launch_bounds__(256, 2) void k1_proj(
    const _Float16* __restrict__ xT, const _Float16* __restrict__ w16,
    const float* __restrict__ tb, const float* __restrict__ pb,
    const float* __restrict__ gb, _Float16* __restrict__ thetaT,
    _Float16* __restrict__ phiT, _Float16* __restrict__ gY) {
  int p = blockIdx.y;
  int b = blockIdx.z;
  int sp0 = blockIdx.x * 128;
  int tid = threadIdx.x;
  int w = tid >> 6;
  int lane = tid & 63;
  int l31 = lane & 31;
  int h = lane >> 5;
  const _Float16* W = w16 + (size_t)p * 32768;
  const float* bias = (p == 0) ? tb : (p == 1) ? pb : gb;
  const _Float16* xTb = xT + ((size_t)b * HW_ + sp0) * C_;
  f32x16 acc[4];
#pragma unroll
  for (int i = 0; i < 4; ++i)
#pragma unroll
    for (int j = 0; j < 16; ++j) acc[i][j] = 0.f;

  if (p < 2) {
    // A = xT rows (m = sp), B = W rows (n = ci). C: col=ci, row=sp.
    int sp = w * 32 + l31;
#pragma unroll
    for (int ks = 0; ks < 16; ++ks) {
      f16x8 a = *(const f16x8*)&xTb[(size_t)sp * C_ + ks * 16 + h * 8];
#pragma unroll
      for (int nt = 0; nt < 4; ++nt) {
        f16x8 bf = *(const f16x8*)&W[(size_t)(nt * 32 + l31) * C_ + ks * 16 + h * 8];
        acc[nt] = mfma16(a, bf, acc[nt]);
      }
    }
    _Float16* out = ((p == 0) ? thetaT : phiT) + (size_t)b * HW_ * CI_;
#pragma unroll
    for (int nt = 0; nt < 4; ++nt) {
      float bv = bias[nt * 32 + l31];
#pragma unroll
      for (int r = 0; r < 16; ++r) {
        int row = (r & 3) + 8 * (r >> 2) + 4 * h;
        int spg = sp0 + w * 32 + row;
        out[(size_t)spg * CI_ + nt * 32 + l31] = (_Float16)(acc[nt][r] + bv);
      }
    }
  } else {
    // A = W rows (m = ci), B = xT rows (n = sp). C: col=sp, row=ci.
#pragma unroll
    for (int ks = 0; ks < 16; ++ks) {
      f16x8 a = *(const f16x8*)&W[(size_t)(w * 32 + l31) * C_ + ks * 16 + h * 8];
#pragma unroll
      for (int nt = 0; nt < 4; ++nt) {
        f16x8 bf = *(const f16x8*)&xTb[(size_t)(nt * 32 + l31) * C_ + ks * 16 + h * 8];
        acc[nt] = mfma16(a, bf, acc[nt]);
      }
    }
    _Float16* gOut = gY + (size_t)b * CI_ * HW_;
#pragma unroll
    for (int r = 0; r < 16; ++r) {
      int ci = w * 32 + (r & 3) + 8 * (r >> 2) + 4 * h;
      float bv = bias[ci];
#pragma unroll
      for (int nt = 0; nt < 4; ++nt)
        gOut[(size_t)ci * HW_ + sp0 + nt * 32 + l31] = (_Float16)(acc[nt][r] + bv);
    }
  }
}

// ---------------- K2: flash attention (S^T orientation) ----------------
// Block: 64 queries; 4 waves = 2 q-strips x 2 key-halves; LDS merge at end.
__global__ __launch_bounds__(256, 1) void k2_attn(
    const _Float16* __restrict__ thetaT, const _Float16* __restrict__ phiT,
    const _Float16* __restrict__ gY, _Float16* __restrict__ attnT) {
  __shared__ _Float16 Pl[4 * 32 * 72];
  __shared__ float Mo[2 * 32 * 132];
  __shared__ float Mml[64 * 2];
  int b = blockIdx.y;
  int q0 = blockIdx.x * 64;
  int tid = threadIdx.x;
  int w = tid >> 6;
  int lane = tid & 63;
  int l31 = lane & 31;
  int h = lane >> 5;
  int qh = w & 1, kh = w >> 1;
  int q = q0 + qh * 32 + l31;
  const _Float16* thb = thetaT + (size_t)b * HW_ * CI_;
  const _Float16* phb = phiT + (size_t)b * HW_ * CI_;
  const _Float16* gvb = gY + (size_t)b * CI_ * HW_;

  f16x8 Bq[8];
#pragma unroll
  for (int ks = 0; ks < 8; ++ks)
    Bq[ks] = *(const f16x8*)&thb[(size_t)q * CI_ + ks * 16 + h * 8];

  f32x16 o[4];
#pragma unroll
  for (int i = 0; i < 4; ++i)
#pragma unroll
    for (int j = 0; j < 16; ++j) o[i][j] = 0.f;
  float m_run = -1e30f, l_run = 0.f;
  _Float16* Plw = &Pl[w * 32 * 72];

  for (int t = 0; t < 32; ++t) {
    int kb = (kh * 32 + t) * 64;
    f32x16 sT[2];
#pragma unroll
    for (int i = 0; i < 2; ++i)
#pragma unroll
      for (int j = 0; j < 16; ++j) sT[i][j] = 0.f;
    // QK^T (transposed): A = phi rows (m=key), B = theta rows (n=q)
#pragma unroll
    for (int ks = 0; ks < 8; ++ks) {
#pragma unroll
      for (int mt = 0; mt < 2; ++mt) {
        f16x8 a = *(const f16x8*)&phb[(size_t)(kb + mt * 32 + l31) * CI_ + ks * 16 + h * 8];
        sT[mt] = mfma16(a, Bq[ks], sT[mt]);
      }
    }
    // online softmax over keys (per column q: in-lane regs + cross-half shuffle)
    float vmax = -1e30f;
#pragma unroll
    for (int mt = 0; mt < 2; ++mt)
#pragma unroll
      for (int r = 0; r < 16; ++r) vmax = fmaxf(vmax, sT[mt][r]);
    vmax = fmaxf(vmax, __shfl_xor(vmax, 32, 64));
    float m_new = fmaxf(m_run, vmax);
    float alpha = __expf(m_run - m_new);
    float psum = 0.f;
#pragma unroll
    for (int mt = 0; mt < 2; ++mt)
#pragma unroll
      for (int r = 0; r < 16; ++r) {
        float pv = __expf(sT[mt][r] - m_new);
        sT[mt][r] = pv;
        psum += pv;
      }
    psum += __shfl_xor(psum, 32, 64);
    l_run = l_run * alpha + psum;
    m_run = m_new;
#pragma unroll
    for (int i = 0; i < 4; ++i)
#pragma unroll
      for (int j = 0; j < 16; ++j) o[i][j] *= alpha;
    // pack P^T into per-wave LDS in [q][key] layout (keys 4-consecutive per reg group)
#pragma unroll
    for (int mt = 0; mt < 2; ++mt)
#pragma unroll
      for (int g4 = 0; g4 < 4; ++g4) {
        f16x4 pk;
#pragma unroll
        for (int j = 0; j < 4; ++j) pk[j] = (_Float16)sT[mt][g4 * 4 + j];
        *(f16x4*)&Plw[l31 * 72 + mt * 32 + g4 * 8 + h * 4] = pk;
      }
    asm volatile("s_waitcnt lgkmcnt(0)" ::: "memory");
    // PV: O^T += g (m=ci) x P^T (n=q)
#pragma unroll
    for (int kv = 0; kv < 4; ++kv) {
      f16x8 bp = *(const f16x8*)&Plw[l31 * 72 + kv * 16 + h * 8];
#pragma unroll
      for (int mt2 = 0; mt2 < 4; ++mt2) {
        f16x8 ag = *(const f16x8*)&gvb[(size_t)(mt2 * 32 + l31) * HW_ + kb + kv * 16 + h * 8];
        o[mt2] = mfma16(ag, bp, o[mt2]);
      }
    }
  }
  __syncthreads();
  if (kh == 1) {
#pragma unroll
    for (int mt2 = 0; mt2 < 4; ++mt2)
#pragma unroll
      for (int g4 = 0; g4 < 4; ++g4) {
        f32x4 v;
#pragma unroll
        for (int j = 0; j < 4; ++j) v[j] = o[mt2][g4 * 4 + j];
        *(f32x4*)&Mo[(qh * 32 + l31) * 132 + mt2 * 32 + g4 * 8 + h * 4] = v;
      }
    Mml[(qh * 32 + l31) * 2 + 0] = m_run;
    Mml[(qh * 32 + l31) * 2 + 1] = l_run;
  }
  __syncthreads();
  if (kh == 0) {
    float m2 = Mml[(qh * 32 + l31) * 2 + 0];
    float l2 = Mml[(qh * 32 + l31) * 2 + 1];
    float mm = fmaxf(m_run, m2);
    float a1 = __expf(m_run - mm), a2 = __expf(m2 - mm);
    float inv = 1.f / (l_run * a1 + l2 * a2);
    _Float16* outp = attnT + (size_t)b * HW_ * CI_;
#pragma unroll
    for (int mt2 = 0; mt2 < 4; ++mt2)
#pragma unroll
      for (int g4 = 0; g4 < 4; ++g4) {
        f32x4 v2 = *(const f32x4*)&Mo[(qh * 32 + l31) * 132 + mt2 * 32 + g4 * 8 + h * 4];
        f16x4 res;
#pragma unroll
        for (int j = 0; j < 4; ++j)
          res[j] = (_Float16)((o[mt2][g4 * 4 + j] * a1 + v2[j] * a2) * inv);
        *(f16x4*)&outp[(size_t)q * CI_ + mt2 * 32 + g4 * 8 + h * 4] = res;
      }
  }
}

// ---------------- K3: out conv (c,hw) + BN stat atomics ----------------
__global__ __launch_bounds__(256, 2) void k3_outconv(
    const _Float16* __restrict__ attnT, const _Float16* __restrict__ wo,
    const float* __restrict__ ob, float* __restrict__ oc,
    float* __restrict__ bnsum) {
  int b = blockIdx.z;
  int c0 = blockIdx.y * 128;
  int s0 = blockIdx.x * 128;
  int tid = threadIdx.x;
  int w = tid >> 6;
  int lane = tid & 63;
  int l31 = lane & 31;
  int h = lane >> 5;
  const _Float16* Bp = attnT + ((size_t)b * HW_ + s0) * CI_;
  f32x16 acc[4];
#pragma unroll
  for (int i = 0; i < 4; ++i)
#pragma unroll
    for (int j = 0; j < 16; ++j) acc[i][j] = 0.f;
  int cA = c0 + w * 32 + l31;
#pragma unroll
  for (int ks = 0; ks < 8; ++ks) {
    f16x8 a = *(const f16x8*)&wo[(size_t)cA * CI_ + ks * 16 + h * 8];
#pragma unroll
    for (int nt = 0; nt < 4; ++nt) {
      f16x8 bf = *(const f16x8*)&Bp[(size_t)(nt * 32 + l31) * CI_ + ks * 16 + h * 8];
      acc[nt] = mfma16(a, bf, acc[nt]);
    }
  }
#pragma unroll
  for (int r = 0; r < 16; ++r) {
    int c = c0 + w * 32 + (r & 3) + 8 * (r >> 2) + 4 * h;
    float bv = ob[c];
    float vs = 0.f, vs2 = 0.f;
#pragma unroll
    for (int nt = 0; nt < 4; ++nt) {
      float v = acc[nt][r] + bv;
      oc[((size_t)(b * C_ + c)) * HW_ + s0 + nt * 32 + l31] = v;
      vs += v;
      vs2 += v * v;
    }
#pragma unroll
    for (int m = 1; m < 32; m <<= 1) {
      vs += __shfl_xor(vs, m, 64);
      vs2 += __shfl_xor(vs2, m, 64);
    }
    if (l31 == 0) {
      atomicAdd(&bnsum[c], vs);
      atomicAdd(&bnsum[C_ + c], vs2);
    }
  }
}

// ---------------- K4: BN (training stats) + ReLU + residual, in place ----------------
__global__ __launch_bounds__(256) void k4_final(
    const float* __restrict__ oc, const float* __restrict__ x,
    const float* __restrict__ bnsum, const float* __restrict__ gamma,
    const float* __restrict__ beta, float* __restrict__ out) {
  int gid = blockIdx.x * 256 + threadIdx.x;
  size_t base = (size_t)gid * 4;
  int c = (int)((base >> 12) & 255);
  float mean = bnsum[c] * (1.f / 16384.f);
  float var = bnsum[C_ + c] * (1.f / 16384.f) - mean * mean;
  float sc = gamma[c] * rsqrtf(var + 1e-5f);
  float bt = beta[c];
  f32x4 v = *(const f32x4*)&oc[base];
  f32x4 xv = *(const f32x4*)&x[base];
  f32x4 r;
#pragma unroll
  for (int j = 0; j < 4; ++j) {
    float y = (v[j] - mean) * sc + bt;
    y = fmaxf(y, 0.f);
    r[j] = y + xv[j];
  }
  *(f32x4*)&out[base] = r;
}

extern "C" void kernel_launch(void* const* d_in, const int* in_sizes, int n_in,
                              void* d_out, int out_size, void* d_ws,
                              size_t ws_size, hipStream_t stream) {
  const float* x = (const float*)d_in[0];
  const float* g_w = (const float*)d_in[1];
  const float* g_b = (const float*)d_in[2];
  const float* th_w = (const float*)d_in[3];
  const float* th_b = (const float*)d_in[4];
  const float* ph_w = (const float*)d_in[5];
  const float* ph_b = (const float*)d_in[6];
  const float* o_w = (const float*)d_in[7];
  const float* o_b = (const float*)d_in[8];
  const float* gam = (const float*)d_in[9];
  const float* bet = (const float*)d_in[10];

  char* ws = (char*)d_ws;
  _Float16* xT = (_Float16*)ws;                            // 8 MB
  _Float16* thetaT = (_Float16*)(ws + 8388608);            // 4 MB
  _Float16* phiT = (_Float16*)(ws + 12582912);             // 4 MB
  _Float16* w16 = (_Float16*)(ws + 16777216);              // 256 KB
  _Float16* gY = (_Float16*)(ws + 17039360);               // 4 MB
  _Float16* attnT = (_Float16*)(ws + 21233664);            // 4 MB
  float* bn = (float*)(ws + 25427968);                     // 2 KB
  float* oc = (float*)d_out;  // out-conv scratch lives in d_out; K4 rewrites in place

  hipMemsetAsync(bn, 0, 2 * C_ * sizeof(float), stream);
  k0_transpose<<<dim3(64, 4, 4), 256, 0, stream>>>(x, xT);
  k0_wconv<<<128, 256, 0, stream>>>(th_w, ph_w, g_w, o_w, w16);
  k1_proj<<<dim3(32, 3, 4), 256, 0, stream>>>(xT, w16, th_b, ph_b, g_b, thetaT,
                                              phiT, gY);
  k2_attn<<<dim3(64, 4), 256, 0, stream>>>(thetaT, phiT, gY, attnT);
  k3_outconv<<<dim3(32, 2, 4), 256, 0, stream>>>(attnT, w16 + 3 * 32768, o_b,
                                                 oc, bn);
  k4_final<<<4096, 256, 0, stream>>>(oc, x, bn, gam, bet, (float*)d_out);
}